// Round 2
// baseline (445.588 us; speedup 1.0000x reference)
//
#include <hip/hip_runtime.h>
#include <stdint.h>

#define E_N 600000
#define N_N 100000

typedef short short8  __attribute__((ext_vector_type(8)));
typedef short short8a __attribute__((ext_vector_type(8), may_alias));
typedef float floatx4 __attribute__((ext_vector_type(4)));

static __device__ __forceinline__ unsigned short f2bf(float f){
  unsigned u = __builtin_bit_cast(unsigned, f);
  unsigned rnd = 0x7fffu + ((u >> 16) & 1u);
  return (unsigned short)((u + rnd) >> 16);
}
static __device__ __forceinline__ unsigned pack2(float a, float b){
  return (unsigned)f2bf(a) | ((unsigned)f2bf(b) << 16);
}

// ---- prep: W1 (384x128) -> w1t bf16 [col][k]; W2 (128x128) -> w2t bf16 [col][k]
__global__ void prep_weights(const float* __restrict__ W1, const float* __restrict__ W2,
                             unsigned short* __restrict__ w1t, unsigned short* __restrict__ w2t){
  int i = blockIdx.x * 256 + threadIdx.x;
  if (i < 384 * 128){
    int c = i / 384, k = i - c * 384;
    w1t[i] = f2bf(W1[k * 128 + c]);
  } else {
    int j = i - 384 * 128;            // grid sized exactly: j < 16384
    int c = j >> 7, k = j & 127;
    w2t[j] = f2bf(W2[k * 128 + c]);
  }
}

// ---- prep: copy nfeat -> output[1]; optionally nfeat f32 -> bf16 in ws
__global__ void prep_nfeat(const float* __restrict__ nf,
                           unsigned* __restrict__ nfbu,      // may be null
                           float* __restrict__ out2){
  const int total = N_N * 128 / 4;
  int stride = gridDim.x * blockDim.x;
  for (int i = blockIdx.x * blockDim.x + threadIdx.x; i < total; i += stride){
    float4 v = reinterpret_cast<const float4*>(nf)[i];
    reinterpret_cast<float4*>(out2)[i] = v;
    if (nfbu){
      nfbu[2 * i]     = pack2(v.x, v.y);
      nfbu[2 * i + 1] = pack2(v.z, v.w);
    }
  }
}

// ---- fused: h = silu(X@W1+b1); y = LN(h@W2+b2)*s+b + efeat
// block = 256 = 4 waves, 32 edges/wave (2 m-frags of 16), N=128 (8 n-frags)
template<bool USE_NFB, bool USE_WT>
__global__ __launch_bounds__(256) void fused_edge(
    const float* __restrict__ efeat,
    const int* __restrict__ src_idx, const int* __restrict__ dst_idx,
    const float* __restrict__ nfeat,
    const unsigned short* __restrict__ nfb,
    const float* __restrict__ W1f, const float* __restrict__ W2f,
    const unsigned short* __restrict__ w1t, const unsigned short* __restrict__ w2t,
    const float* __restrict__ b1, const float* __restrict__ b2,
    const float* __restrict__ lns, const float* __restrict__ lnb,
    float* __restrict__ out)
{
  // per-wave private h^T tile: [m(2)][chan(128)][edge(16)] u16 — accessed ONLY as u16
  __shared__ unsigned short hT[4][2][128][16];

  const int tid  = threadIdx.x;
  const int w    = tid >> 6;
  const int lane = tid & 63;
  const int r    = lane & 15;     // A row / B col / C col
  const int g    = lane >> 4;     // k-group; C row = 4g+q

  const int eb = blockIdx.x * 128 + w * 32;

  int er[2];
  #pragma unroll
  for (int m = 0; m < 2; ++m){
    int e = eb + 16 * m + r;
    er[m] = e < E_N ? e : (E_N - 1);
  }
  int gidx[2][2];
  #pragma unroll
  for (int m = 0; m < 2; ++m){
    int si = src_idx[er[m]];
    int di = dst_idx[er[m]];
    si = si < 0 ? 0 : (si >= N_N ? N_N - 1 : si);
    di = di < 0 ? 0 : (di >= N_N ? N_N - 1 : di);
    gidx[0][m] = si;
    gidx[1][m] = di;
  }

  auto loadA_f32 = [&](const float* p) -> short8 {
    float4 v0 = reinterpret_cast<const float4*>(p)[0];
    float4 v1 = reinterpret_cast<const float4*>(p)[1];
    short8 t;
    t[0] = (short)f2bf(v0.x); t[1] = (short)f2bf(v0.y);
    t[2] = (short)f2bf(v0.z); t[3] = (short)f2bf(v0.w);
    t[4] = (short)f2bf(v1.x); t[5] = (short)f2bf(v1.y);
    t[6] = (short)f2bf(v1.z); t[7] = (short)f2bf(v1.w);
    return t;
  };
  auto loadB1 = [&](int n, int kk) -> short8 {   // W1 column 16n+r, k = kk..kk+7
    if constexpr (USE_WT){
      return *reinterpret_cast<const short8a*>(w1t + (16 * n + r) * 384 + kk);
    } else {
      short8 t;
      #pragma unroll
      for (int j = 0; j < 8; ++j) t[j] = (short)f2bf(W1f[(kk + j) * 128 + 16 * n + r]);
      return t;
    }
  };
  auto loadB2 = [&](int n, int kk) -> short8 {
    if constexpr (USE_WT){
      return *reinterpret_cast<const short8a*>(w2t + (16 * n + r) * 128 + kk);
    } else {
      short8 t;
      #pragma unroll
      for (int j = 0; j < 8; ++j) t[j] = (short)f2bf(W2f[(kk + j) * 128 + 16 * n + r]);
      return t;
    }
  };

  floatx4 acc1[2][8];
  #pragma unroll
  for (int m = 0; m < 2; ++m)
    #pragma unroll
    for (int n = 0; n < 8; ++n)
      acc1[m][n] = (floatx4){0.f, 0.f, 0.f, 0.f};

  // ---- GEMM1 seg 0: efeat (f32 -> bf16 on the fly)
  #pragma unroll
  for (int ks = 0; ks < 4; ++ks){
    short8 a0 = loadA_f32(efeat + (size_t)er[0] * 128 + ks * 32 + 8 * g);
    short8 a1 = loadA_f32(efeat + (size_t)er[1] * 128 + ks * 32 + 8 * g);
    #pragma unroll
    for (int n = 0; n < 8; ++n){
      short8 b = loadB1(n, ks * 32 + 8 * g);
      acc1[0][n] = __builtin_amdgcn_mfma_f32_16x16x32_bf16(a0, b, acc1[0][n], 0, 0, 0);
      acc1[1][n] = __builtin_amdgcn_mfma_f32_16x16x32_bf16(a1, b, acc1[1][n], 0, 0, 0);
    }
  }
  // ---- GEMM1 seg 1,2: gathered nfeat
  #pragma unroll
  for (int s = 0; s < 2; ++s){
    #pragma unroll
    for (int ks = 0; ks < 4; ++ks){
      short8 a0, a1;
      if constexpr (USE_NFB){
        a0 = *reinterpret_cast<const short8a*>(nfb + (size_t)gidx[s][0] * 128 + ks * 32 + 8 * g);
        a1 = *reinterpret_cast<const short8a*>(nfb + (size_t)gidx[s][1] * 128 + ks * 32 + 8 * g);
      } else {
        a0 = loadA_f32(nfeat + (size_t)gidx[s][0] * 128 + ks * 32 + 8 * g);
        a1 = loadA_f32(nfeat + (size_t)gidx[s][1] * 128 + ks * 32 + 8 * g);
      }
      #pragma unroll
      for (int n = 0; n < 8; ++n){
        short8 b = loadB1(n, (s + 1) * 128 + ks * 32 + 8 * g);
        acc1[0][n] = __builtin_amdgcn_mfma_f32_16x16x32_bf16(a0, b, acc1[0][n], 0, 0, 0);
        acc1[1][n] = __builtin_amdgcn_mfma_f32_16x16x32_bf16(a1, b, acc1[1][n], 0, 0, 0);
      }
    }
  }

  // ---- epilogue 1: +b1, silu, ->bf16, h^T into wave-private LDS (plain u16 stores)
  float b1v[8];
  #pragma unroll
  for (int n = 0; n < 8; ++n) b1v[n] = b1[16 * n + r];
  #pragma unroll
  for (int m = 0; m < 2; ++m){
    #pragma unroll
    for (int n = 0; n < 8; ++n){
      #pragma unroll
      for (int q = 0; q < 4; ++q){
        float x = acc1[m][n][q] + b1v[n];
        float sv = x / (1.f + __expf(-x));     // silu
        hT[w][m][16 * n + r][4 * g + q] = f2bf(sv);
      }
    }
  }

  // ---- GEMM2: y = h @ W2  (A-frags via plain u16 reads from h^T)
  floatx4 acc2[2][8];
  #pragma unroll
  for (int m = 0; m < 2; ++m)
    #pragma unroll
    for (int n = 0; n < 8; ++n)
      acc2[m][n] = (floatx4){0.f, 0.f, 0.f, 0.f};

  #pragma unroll
  for (int ks = 0; ks < 4; ++ks){
    short8 a0, a1;
    #pragma unroll
    for (int i = 0; i < 8; ++i){
      a0[i] = (short)hT[w][0][ks * 32 + 8 * g + i][r];
      a1[i] = (short)hT[w][1][ks * 32 + 8 * g + i][r];
    }
    #pragma unroll
    for (int n = 0; n < 8; ++n){
      short8 b = loadB2(n, ks * 32 + 8 * g);
      acc2[0][n] = __builtin_amdgcn_mfma_f32_16x16x32_bf16(a0, b, acc2[0][n], 0, 0, 0);
      acc2[1][n] = __builtin_amdgcn_mfma_f32_16x16x32_bf16(a1, b, acc2[1][n], 0, 0, 0);
    }
  }

  // ---- epilogue 2: +b2, LayerNorm (16-lane shfl reduce), *scale+bias, +efeat, store
  float b2v[8], lsv[8], lbv[8];
  #pragma unroll
  for (int n = 0; n < 8; ++n){
    b2v[n] = b2[16 * n + r];
    lsv[n] = lns[16 * n + r];
    lbv[n] = lnb[16 * n + r];
  }
  #pragma unroll
  for (int m = 0; m < 2; ++m){
    #pragma unroll
    for (int q = 0; q < 4; ++q){
      float s1 = 0.f, s2 = 0.f;
      #pragma unroll
      for (int n = 0; n < 8; ++n){
        float v = acc2[m][n][q] + b2v[n];
        s1 += v; s2 += v * v;
      }
      #pragma unroll
      for (int mk = 1; mk < 16; mk <<= 1){
        s1 += __shfl_xor(s1, mk);
        s2 += __shfl_xor(s2, mk);
      }
      float mu   = s1 * (1.f / 128.f);
      float var  = s2 * (1.f / 128.f) - mu * mu;
      var = var > 0.f ? var : 0.f;
      float rstd = rsqrtf(var + 1e-5f);
      int e = eb + 16 * m + 4 * g + q;
      if (e < E_N){
        const float* ef = efeat + (size_t)e * 128;
        float*       op = out   + (size_t)e * 128;
        #pragma unroll
        for (int n = 0; n < 8; ++n){
          float v = acc2[m][n][q] + b2v[n];
          op[16 * n + r] = (v - mu) * rstd * lsv[n] + lbv[n] + ef[16 * n + r];
        }
      }
    }
  }
}

extern "C" void kernel_launch(void* const* d_in, const int* in_sizes, int n_in,
                              void* d_out, int out_size, void* d_ws, size_t ws_size,
                              hipStream_t stream){
  const float* efeat = (const float*)d_in[0];
  const float* nfeat = (const float*)d_in[1];
  const int*   srci  = (const int*)d_in[2];
  const int*   dsti  = (const int*)d_in[3];
  const float* W1    = (const float*)d_in[4];
  const float* b1    = (const float*)d_in[5];
  const float* W2    = (const float*)d_in[6];
  const float* b2    = (const float*)d_in[7];
  const float* lns   = (const float*)d_in[8];
  const float* lnb   = (const float*)d_in[9];
  float* out = (float*)d_out;

  const size_t NEED_W   = (size_t)(384 * 128 + 128 * 128) * 2;   // 131,072 B
  const size_t NEED_NFB = (size_t)N_N * 128 * 2;                 // 25,600,000 B
  const bool wt_ok  = ws_size >= NEED_W;
  const bool nfb_ok = ws_size >= NEED_W + NEED_NFB;

  char* ws = (char*)d_ws;
  unsigned short* w1t = wt_ok  ? (unsigned short*)ws : nullptr;
  unsigned short* w2t = wt_ok  ? w1t + 384 * 128 : nullptr;
  unsigned short* nfb = nfb_ok ? (unsigned short*)(ws + NEED_W) : nullptr;

  if (wt_ok)
    prep_weights<<<(384 * 128 + 128 * 128) / 256, 256, 0, stream>>>(W1, W2, w1t, w2t);
  prep_nfeat<<<2048, 256, 0, stream>>>(nfeat, (unsigned*)nfb, out + (size_t)E_N * 128);

  int blocks = (E_N + 127) / 128;
  if (nfb_ok)
    fused_edge<true , true ><<<blocks, 256, 0, stream>>>(efeat, srci, dsti, nfeat, nfb,
                                                         W1, W2, w1t, w2t, b1, b2, lns, lnb, out);
  else if (wt_ok)
    fused_edge<false, true ><<<blocks, 256, 0, stream>>>(efeat, srci, dsti, nfeat, nfb,
                                                         W1, W2, w1t, w2t, b1, b2, lns, lnb, out);
  else
    fused_edge<false, false><<<blocks, 256, 0, stream>>>(efeat, srci, dsti, nfeat, nfb,
                                                         W1, W2, w1t, w2t, b1, b2, lns, lnb, out);
}